// Round 7
// baseline (711.322 us; speedup 1.0000x reference)
//
#include <hip/hip_runtime.h>
#include <stdint.h>

#define DEV __device__ __forceinline__

typedef unsigned short u16;
using f32x4  = __attribute__((ext_vector_type(4))) float;
using bf16x8 = __attribute__((ext_vector_type(8))) short;

constexpr int B_  = 4;
constexpr int L_  = 8192;
constexpr int D_  = 1024;
constexpr int M_  = B_ * L_;    // 32768
constexpr int K_  = D_;         // 1024
constexpr int CCH = 128;        // chunks per sequence
constexpr int TCH = L_ / CCH;   // 64 steps per chunk
constexpr int NKT = K_ / 64;    // 16 K-tiles of 64

DEV u16 f2bf(float f) {
  uint32_t u = __float_as_uint(f);
  u += 0x7fffu + ((u >> 16) & 1u);
  return (u16)(u >> 16);
}
DEV float bf2f(u16 h) { return __uint_as_float(((uint32_t)h) << 16); }

DEV void async16(const void* g, const void* l) {
  __builtin_amdgcn_global_load_lds(
      (const __attribute__((address_space(1))) unsigned int*)g,
      (__attribute__((address_space(3))) unsigned int*)l, 16, 0, 0);
}

#define VM8 asm volatile("s_waitcnt vmcnt(8)" ::: "memory")
#define VM4 asm volatile("s_waitcnt vmcnt(4)" ::: "memory")
#define VM0 asm volatile("s_waitcnt vmcnt(0)" ::: "memory")
#define LGKM0 asm volatile("s_waitcnt lgkmcnt(0)" ::: "memory")
#define BAR() do { __builtin_amdgcn_s_barrier(); asm volatile("" ::: "memory"); } while (0)

// ---------------- fp32 -> bf16 convert (n8 = count/8) ----------------
__global__ void cvt_kernel(const float* __restrict__ src, u16* __restrict__ dst, int n8) {
  int stride = gridDim.x * blockDim.x;
  for (int i = blockIdx.x * blockDim.x + threadIdx.x; i < n8; i += stride) {
    float4 a = reinterpret_cast<const float4*>(src)[2 * i];
    float4 b = reinterpret_cast<const float4*>(src)[2 * i + 1];
    union { u16 u[8]; uint4 v; } r;
    r.u[0] = f2bf(a.x); r.u[1] = f2bf(a.y); r.u[2] = f2bf(a.z); r.u[3] = f2bf(a.w);
    r.u[4] = f2bf(b.x); r.u[5] = f2bf(b.y); r.u[6] = f2bf(b.z); r.u[7] = f2bf(b.w);
    reinterpret_cast<uint4*>(dst)[i] = r.v;
  }
}

__global__ void cvt_w_kernel(const float* __restrict__ w0, const float* __restrict__ w1,
                             const float* __restrict__ w2, const float* __restrict__ w3,
                             u16* __restrict__ dcat, u16* __restrict__ d3) {
  constexpr int SEG = K_ * D_ / 8;
  int stride = gridDim.x * blockDim.x;
  for (int i = blockIdx.x * blockDim.x + threadIdx.x; i < 4 * SEG; i += stride) {
    int seg = i / SEG, off = i - seg * SEG;
    const float* src = seg == 0 ? w0 : (seg == 1 ? w1 : (seg == 2 ? w2 : w3));
    u16* dst = seg == 3 ? d3 : (dcat + (size_t)seg * K_ * D_);
    float4 a = reinterpret_cast<const float4*>(src)[2 * off];
    float4 b = reinterpret_cast<const float4*>(src)[2 * off + 1];
    union { u16 u[8]; uint4 v; } r;
    r.u[0] = f2bf(a.x); r.u[1] = f2bf(a.y); r.u[2] = f2bf(a.z); r.u[3] = f2bf(a.w);
    r.u[4] = f2bf(b.x); r.u[5] = f2bf(b.y); r.u[6] = f2bf(b.z); r.u[7] = f2bf(b.w);
    reinterpret_cast<uint4*>(dst)[off] = r.v;
  }
}

// ============ 256x256 GEMM mainloop: 8-phase counted-vmcnt pipeline ==========
// 8 waves (2M x 4N), BK=64 split into two 32-col k-halves. LDS per matrix:
// [2 buf][2 kk][256 rows][32 cols] (16KB per half, 64KB/matrix, 128KB total).
// 64B row stride => DMA writes linear & fragment reads naturally bank-spread
// (no swizzle needed). Per phase: ds_read subtile + stage 1 half-tile + 16 MFMA;
// vmcnt(8) only at phase ends 1 and 3 (2 per K-tile) - never drains in loop.
// Staging runs 6 phases ahead of consumption; every stage target's prior reads
// are closed by an intervening end-of-phase barrier (after all waves' lgkmcnt).

// stage one [256 x 32] half: 2 x global_load_lds(16B) per thread, linear LDS dst
DEV void stage_half(const u16* __restrict__ G, int row0, int kcol, u16* dst, int tid) {
#pragma unroll
  for (int t = 0; t < 2; ++t) {
    int l = t * 512 + tid;
    int row = l >> 2, sl = l & 3;
    async16(G + (size_t)(row0 + row) * K_ + kcol + sl * 8, dst + l * 8);
  }
}

DEV void mfma16(f32x4 acc[8][4], const bf16x8 af[4], const bf16x8 bf[4], int h) {
  __builtin_amdgcn_s_setprio(1);
#pragma unroll
  for (int i = 0; i < 4; ++i)
#pragma unroll
    for (int j = 0; j < 4; ++j)
      acc[h * 4 + i][j] =
          __builtin_amdgcn_mfma_f32_16x16x32_bf16(af[i], bf[j], acc[h * 4 + i][j], 0, 0, 0);
  __builtin_amdgcn_s_setprio(0);
}

DEV void gemm_mainloop256(const u16* __restrict__ Ag, const u16* __restrict__ Bg,
                          int m0, int n0, u16* LdsA, u16* LdsB, f32x4 acc[8][4]) {
  const int tid = threadIdx.x, lane = tid & 63, wid = tid >> 6;
  const int wr = wid >> 2, wc = wid & 3;
  const int g0 = lane >> 4, l15 = lane & 15;

  auto AH = [&](int buf, int kk) { return LdsA + (buf * 2 + kk) * 8192; };
  auto BH = [&](int buf, int kk) { return LdsB + (buf * 2 + kk) * 8192; };

  // prologue: tile0 {Ak0,Bk0,Ak1,Bk1}, tile1 {Ak0,Bk0}  (6 halves, 12 loads)
  stage_half(Ag, m0, 0,  AH(0, 0), tid);
  stage_half(Bg, n0, 0,  BH(0, 0), tid);
  stage_half(Ag, m0, 32, AH(0, 1), tid);
  stage_half(Bg, n0, 32, BH(0, 1), tid);
  stage_half(Ag, m0, 64, AH(1, 0), tid);
  stage_half(Bg, n0, 64, BH(1, 0), tid);
  VM8;   // tile0 kk0 (A+B) landed; 4 newer halves stay in flight
  BAR();

  const int arow = wr * 128 + l15;
  const int brow = wc * 64 + l15;
  bf16x8 af[4], bf[4];

#define LOADA(P, RB)                                                        \
  _Pragma("unroll") for (int i = 0; i < 4; ++i)                             \
      af[i] = *reinterpret_cast<const bf16x8*>((P) + (RB + i * 16) * 32 + g0 * 8)
#define LOADB(P)                                                            \
  _Pragma("unroll") for (int j = 0; j < 4; ++j)                             \
      bf[j] = *reinterpret_cast<const bf16x8*>((P) + (brow + j * 16) * 32 + g0 * 8)

  for (int v = 0; v < NKT; ++v) {
    const int par = v & 1;
    const u16* Ak0 = AH(par, 0); const u16* Ak1 = AH(par, 1);
    const u16* Bk0 = BH(par, 0); const u16* Bk1 = BH(par, 1);

    // ---- p0: af(h0,kk0)+bfr(kk0); stage A kk1 of tile v+1 -> other buf
    LOADA(Ak0, arow); LOADB(Bk0);
    if (v + 1 < NKT) stage_half(Ag, m0, (v + 1) * 64 + 32, AH(par ^ 1, 1), tid);
    LGKM0; __builtin_amdgcn_sched_barrier(0);
    mfma16(acc, af, bf, 0);
    BAR();

    // ---- p1: af(h1,kk0) (bfr kk0 kept in regs); stage B kk1 of v+1
    LOADA(Ak0, arow + 64);
    if (v + 1 < NKT) stage_half(Bg, n0, (v + 1) * 64 + 32, BH(par ^ 1, 1), tid);
    LGKM0; __builtin_amdgcn_sched_barrier(0);
    mfma16(acc, af, bf, 1);
    if (v < NKT - 1) { VM8; } else { VM0; }   // confirm kk1(v) landed
    BAR();

    // ---- p2: af(h0,kk1)+bfr(kk1); stage A kk0 of tile v+2 -> same buf (region free)
    LOADA(Ak1, arow); LOADB(Bk1);
    if (v + 2 < NKT) stage_half(Ag, m0, (v + 2) * 64, AH(par, 0), tid);
    LGKM0; __builtin_amdgcn_sched_barrier(0);
    mfma16(acc, af, bf, 0);
    BAR();

    // ---- p3: af(h1,kk1); stage B kk0 of v+2
    LOADA(Ak1, arow + 64);
    if (v + 2 < NKT) stage_half(Bg, n0, (v + 2) * 64, BH(par, 0), tid);
    LGKM0; __builtin_amdgcn_sched_barrier(0);
    mfma16(acc, af, bf, 1);
    if (v < NKT - 2) { VM8; BAR(); }          // confirm kk0(v+1) landed
    else if (v == NKT - 2) { VM4; BAR(); }
    // v == NKT-1: loop ends, nothing outstanding (VM0 at p1 drained)
  }
#undef LOADA
#undef LOADB
}

DEV int xcd_swizzle(int bid, int nwg) {   // nwg % 8 == 0 always here
  int cpx = nwg >> 3;
  return (bid & 7) * cpx + (bid >> 3);
}

// ---------------- projection GEMM: N = 3072 (dt | zpre | ya) ----------------
__global__ __launch_bounds__(512, 2) void gemm_proj_kernel(
    const u16* __restrict__ xb, const u16* __restrict__ Wcat,
    const float* __restrict__ b_dt, const float* __restrict__ b_lnz,
    const float* __restrict__ b_ya,
    u16* __restrict__ dtb, u16* __restrict__ zpb, u16* __restrict__ syab) {
  __shared__ __align__(16) u16 LdsA[2 * 2 * 8192];
  __shared__ __align__(16) u16 LdsB[2 * 2 * 8192];
  f32x4 acc[8][4] = {};

  constexpr int NT = 3 * D_ / 256;   // 12 n-tiles
  int swz = xcd_swizzle(blockIdx.x, gridDim.x);
  const int m0 = (swz / NT) * 256;
  const int n0 = (swz % NT) * 256;
  gemm_mainloop256(xb, Wcat, m0, n0, LdsA, LdsB, acc);

  const int tid = threadIdx.x, lane = tid & 63, wid = tid >> 6;
  const int wr = wid >> 2, wc = wid & 3;
  const int proj  = n0 >> 10;        // 256-tile lies fully inside one projection
  const int dbase = n0 & 1023;
  const float* bias = proj == 0 ? b_dt : (proj == 1 ? b_lnz : b_ya);
  u16* outp = proj == 0 ? dtb : (proj == 1 ? zpb : syab);
#pragma unroll
  for (int i = 0; i < 8; ++i) {
    int mr = m0 + wr * 128 + i * 16 + (lane >> 4) * 4;
#pragma unroll
    for (int j = 0; j < 4; ++j) {
      int nc = dbase + wc * 64 + j * 16 + (lane & 15);
      float bv = bias[nc];
#pragma unroll
      for (int r = 0; r < 4; ++r) {
        float v = acc[i][j][r] + bv;
        if (proj == 2) v = v / (1.f + __expf(-v));   // silu
        outp[(size_t)(mr + r) * D_ + nc] = f2bf(v);
      }
    }
  }
}

// ---------------- output GEMM: y = (h@w_y^T + b_y) * silu(ya) ----------------
__global__ __launch_bounds__(512, 2) void gemm_out_kernel(
    const u16* __restrict__ hb, const u16* __restrict__ Wyb,
    const float* __restrict__ b_y, const u16* __restrict__ syab,
    float* __restrict__ y) {
  __shared__ __align__(16) u16 LdsA[2 * 2 * 8192];
  __shared__ __align__(16) u16 LdsB[2 * 2 * 8192];
  f32x4 acc[8][4] = {};

  constexpr int NT = D_ / 256;       // 4 n-tiles
  int swz = xcd_swizzle(blockIdx.x, gridDim.x);
  const int m0 = (swz / NT) * 256;
  const int n0 = (swz % NT) * 256;
  gemm_mainloop256(hb, Wyb, m0, n0, LdsA, LdsB, acc);

  const int tid = threadIdx.x, lane = tid & 63, wid = tid >> 6;
  const int wr = wid >> 2, wc = wid & 3;
#pragma unroll
  for (int i = 0; i < 8; ++i) {
    int mr = m0 + wr * 128 + i * 16 + (lane >> 4) * 4;
#pragma unroll
    for (int j = 0; j < 4; ++j) {
      int nc = n0 + wc * 64 + j * 16 + (lane & 15);
      float bv = b_y[nc];
#pragma unroll
      for (int r = 0; r < 4; ++r) {
        float v = acc[i][j][r] + bv;
        float s = bf2f(syab[(size_t)(mr + r) * D_ + nc]);
        y[(size_t)(mr + r) * D_ + nc] = v * s;
      }
    }
  }
}

// ---------------- chunked scan: h_t = a_t h_{t-1} + z_t da_t ----------------
__global__ void scan1_kernel(const u16* __restrict__ dtb, const u16* __restrict__ zpb,
                             float* __restrict__ Ach, float* __restrict__ Bch) {
  const int b = blockIdx.x / CCH;
  const int c = blockIdx.x % CCH;
  const int d0 = threadIdx.x * 4;
  const size_t base = ((size_t)(b * L_ + c * TCH)) * D_ + d0;
  float h[4]  = {0.f, 0.f, 0.f, 0.f};
  float Ap[4] = {1.f, 1.f, 1.f, 1.f};
#pragma unroll 4
  for (int t = 0; t < TCH; ++t) {
    ushort4 du = *reinterpret_cast<const ushort4*>(dtb + base + (size_t)t * D_);
    ushort4 zu = *reinterpret_cast<const ushort4*>(zpb + base + (size_t)t * D_);
    const u16* dp = reinterpret_cast<const u16*>(&du);
    const u16* zz = reinterpret_cast<const u16*>(&zu);
#pragma unroll
    for (int q = 0; q < 4; ++q) {
      float dt = bf2f(dp[q]);
      float zv = bf2f(zz[q]);
      float a  = 1.f / (1.f + __expf(dt));    // sigmoid(-dt)
      float da = 1.f - a;                     // sigmoid(dt)
      float z  = 1.f / (1.f + __expf(-zv));   // sigmoid(zpre)
      h[q]  = a * h[q] + z * da;
      Ap[q] *= a;
    }
  }
  const size_t o = ((size_t)(b * CCH + c)) * D_ + d0;
  *reinterpret_cast<float4*>(Ach + o) = make_float4(Ap[0], Ap[1], Ap[2], Ap[3]);
  *reinterpret_cast<float4*>(Bch + o) = make_float4(h[0], h[1], h[2], h[3]);
}

__global__ void scan2_kernel(const float* __restrict__ Ach, const float* __restrict__ Bch,
                             const float* __restrict__ h0, float* __restrict__ Hin) {
  const int b = blockIdx.x >> 2;
  const int d = (blockIdx.x & 3) * 256 + threadIdx.x;
  float carry = h0[d];
  for (int c = 0; c < CCH; ++c) {
    const size_t o = ((size_t)(b * CCH + c)) * D_ + d;
    Hin[o] = carry;
    carry = Ach[o] * carry + Bch[o];
  }
}

__global__ void scan3_kernel(const u16* __restrict__ dtb, const u16* __restrict__ zpb,
                             const float* __restrict__ Hin, u16* __restrict__ hb) {
  const int b = blockIdx.x / CCH;
  const int c = blockIdx.x % CCH;
  const int d0 = threadIdx.x * 4;
  const size_t base = ((size_t)(b * L_ + c * TCH)) * D_ + d0;
  float4 hv = *reinterpret_cast<const float4*>(Hin + ((size_t)(b * CCH + c)) * D_ + d0);
  float h[4] = {hv.x, hv.y, hv.z, hv.w};
#pragma unroll 4
  for (int t = 0; t < TCH; ++t) {
    ushort4 du = *reinterpret_cast<const ushort4*>(dtb + base + (size_t)t * D_);
    ushort4 zu = *reinterpret_cast<const ushort4*>(zpb + base + (size_t)t * D_);
    const u16* dp = reinterpret_cast<const u16*>(&du);
    const u16* zz = reinterpret_cast<const u16*>(&zu);
    ushort4 ov;
    u16* op = reinterpret_cast<u16*>(&ov);
#pragma unroll
    for (int q = 0; q < 4; ++q) {
      float dt = bf2f(dp[q]);
      float zv = bf2f(zz[q]);
      float a  = 1.f / (1.f + __expf(dt));
      float da = 1.f - a;
      float z  = 1.f / (1.f + __expf(-zv));
      h[q] = a * h[q] + z * da;
      op[q] = f2bf(h[q]);
    }
    *reinterpret_cast<ushort4*>(hb + base + (size_t)t * D_) = ov;
  }
}

extern "C" void kernel_launch(void* const* d_in, const int* in_sizes, int n_in,
                              void* d_out, int out_size, void* d_ws, size_t ws_size,
                              hipStream_t stream) {
  const float* x     = (const float*)d_in[0];
  const float* w_lnz = (const float*)d_in[1];
  const float* b_lnz = (const float*)d_in[2];
  const float* w_dt  = (const float*)d_in[3];
  const float* b_dt  = (const float*)d_in[4];
  const float* w_y   = (const float*)d_in[5];
  const float* b_y   = (const float*)d_in[6];
  const float* w_ya  = (const float*)d_in[7];
  const float* b_ya  = (const float*)d_in[8];
  const float* h0    = (const float*)d_in[9];
  float* y = (float*)d_out;

  char* ws = (char*)d_ws;
  const size_t MB = 1024ull * 1024ull;
  u16*   xb   = (u16*)(ws);               // 64MB  bf16 x
  u16*   Wcat = (u16*)(ws + 64 * MB);     // 6MB   [w_dt; w_ln_z; w_ya]
  u16*   Wyb  = (u16*)(ws + 70 * MB);     // 2MB   w_y
  u16*   dtb  = (u16*)(ws + 72 * MB);     // 64MB
  u16*   zpb  = (u16*)(ws + 136 * MB);    // 64MB
  u16*   syab = (u16*)(ws + 200 * MB);    // 64MB  silu(ya)
  u16*   hb   = (u16*)(ws + 264 * MB);    // 64MB  h (bf16)
  float* Ach  = (float*)(ws + 328 * MB);  // 2MB
  float* Bch  = (float*)(ws + 330 * MB);  // 2MB
  float* Hin  = (float*)(ws + 332 * MB);  // 2MB

  // converts
  cvt_kernel<<<2048, 256, 0, stream>>>(x, xb, M_ * K_ / 8);
  cvt_w_kernel<<<1024, 256, 0, stream>>>(w_dt, w_lnz, w_ya, w_y, Wcat, Wyb);

  // fused 3-projection GEMM (256^2 tiles, 8-phase pipeline)
  gemm_proj_kernel<<<(M_ / 256) * (3 * D_ / 256), 512, 0, stream>>>(
      xb, Wcat, b_dt, b_lnz, b_ya, dtb, zpb, syab);

  // chunked scan
  scan1_kernel<<<B_ * CCH, 256, 0, stream>>>(dtb, zpb, Ach, Bch);
  scan2_kernel<<<16, 256, 0, stream>>>(Ach, Bch, h0, Hin);
  scan3_kernel<<<B_ * CCH, 256, 0, stream>>>(dtb, zpb, Hin, hb);

  // output GEMM fused with silu gate
  gemm_out_kernel<<<(M_ / 256) * (D_ / 256), 512, 0, stream>>>(
      hb, Wyb, b_y, syab, y);
}

// Round 9
// 699.867 us; speedup vs baseline: 1.0164x; 1.0164x over previous
//
#include <hip/hip_runtime.h>
#include <stdint.h>

#define DEV __device__ __forceinline__

typedef unsigned short u16;
using f32x4  = __attribute__((ext_vector_type(4))) float;
using bf16x8 = __attribute__((ext_vector_type(8))) short;

constexpr int B_  = 4;
constexpr int L_  = 8192;
constexpr int D_  = 1024;
constexpr int M_  = B_ * L_;    // 32768
constexpr int K_  = D_;         // 1024
constexpr int CCH = 128;        // chunks per sequence
constexpr int TCH = L_ / CCH;   // 64 steps per chunk
constexpr int NKT = K_ / 64;    // 16 K-tiles of 64

DEV u16 f2bf(float f) {
  uint32_t u = __float_as_uint(f);
  u += 0x7fffu + ((u >> 16) & 1u);
  return (u16)(u >> 16);
}
DEV float bf2f(u16 h) { return __uint_as_float(((uint32_t)h) << 16); }

DEV void async16(const void* g, const void* l) {
  __builtin_amdgcn_global_load_lds(
      (const __attribute__((address_space(1))) unsigned int*)g,
      (__attribute__((address_space(3))) unsigned int*)l, 16, 0, 0);
}

#define VM8 asm volatile("s_waitcnt vmcnt(8)" ::: "memory")
#define VM4 asm volatile("s_waitcnt vmcnt(4)" ::: "memory")
#define VM0 asm volatile("s_waitcnt vmcnt(0)" ::: "memory")
#define LGKM0 asm volatile("s_waitcnt lgkmcnt(0)" ::: "memory")
#define BAR() do { __builtin_amdgcn_s_barrier(); asm volatile("" ::: "memory"); } while (0)

// ---------------- fp32 -> bf16 convert (n8 = count/8) ----------------
__global__ void cvt_kernel(const float* __restrict__ src, u16* __restrict__ dst, int n8) {
  int stride = gridDim.x * blockDim.x;
  for (int i = blockIdx.x * blockDim.x + threadIdx.x; i < n8; i += stride) {
    float4 a = reinterpret_cast<const float4*>(src)[2 * i];
    float4 b = reinterpret_cast<const float4*>(src)[2 * i + 1];
    union { u16 u[8]; uint4 v; } r;
    r.u[0] = f2bf(a.x); r.u[1] = f2bf(a.y); r.u[2] = f2bf(a.z); r.u[3] = f2bf(a.w);
    r.u[4] = f2bf(b.x); r.u[5] = f2bf(b.y); r.u[6] = f2bf(b.z); r.u[7] = f2bf(b.w);
    reinterpret_cast<uint4*>(dst)[i] = r.v;
  }
}

__global__ void cvt_w_kernel(const float* __restrict__ w0, const float* __restrict__ w1,
                             const float* __restrict__ w2, const float* __restrict__ w3,
                             u16* __restrict__ dcat, u16* __restrict__ d3) {
  constexpr int SEG = K_ * D_ / 8;
  int stride = gridDim.x * blockDim.x;
  for (int i = blockIdx.x * blockDim.x + threadIdx.x; i < 4 * SEG; i += stride) {
    int seg = i / SEG, off = i - seg * SEG;
    const float* src = seg == 0 ? w0 : (seg == 1 ? w1 : (seg == 2 ? w2 : w3));
    u16* dst = seg == 3 ? d3 : (dcat + (size_t)seg * K_ * D_);
    float4 a = reinterpret_cast<const float4*>(src)[2 * off];
    float4 b = reinterpret_cast<const float4*>(src)[2 * off + 1];
    union { u16 u[8]; uint4 v; } r;
    r.u[0] = f2bf(a.x); r.u[1] = f2bf(a.y); r.u[2] = f2bf(a.z); r.u[3] = f2bf(a.w);
    r.u[4] = f2bf(b.x); r.u[5] = f2bf(b.y); r.u[6] = f2bf(b.z); r.u[7] = f2bf(b.w);
    reinterpret_cast<uint4*>(dst)[off] = r.v;
  }
}

// ============ 256x256 GEMM mainloop: 8-phase counted-vmcnt pipeline ==========
// 8 waves (2M x 4N), BK=64 split into two 32-col k-halves. LDS per matrix:
// [2 buf][2 kk][256 rows][4 slots of 16B] (16KB/half, 128KB total).
// BANK SWIZZLE (round-7 fix): physical slot = s ^ ((row>>1)&3), applied as
// pre-swizzled GLOBAL source column (linear DMA dest, rule #21) and as a
// per-lane constant offset on ds_read. Over 16 lanes (row&1,(row>>1)&3)
// covers all 8 (parity,slot) combos twice -> 2-way bank aliasing (free).
// Per phase: ds_read subtile + stage 1 half-tile + 16 MFMA; vmcnt(8) twice
// per K-tile, never drained in-loop; staging runs 6 phases ahead.

DEV void stage_half(const u16* __restrict__ G, int row0, int kcol, u16* dst, int tid) {
#pragma unroll
  for (int t = 0; t < 2; ++t) {
    int l = t * 512 + tid;
    int row = l >> 2, sl = l & 3;
    int col = (sl ^ ((row >> 1) & 3)) * 8;   // pre-swizzled source column
    async16(G + (size_t)(row0 + row) * K_ + kcol + col, dst + l * 8);
  }
}

DEV void mfma16(f32x4 acc[8][4], const bf16x8 af[4], const bf16x8 bf[4], int h) {
  __builtin_amdgcn_s_setprio(1);
#pragma unroll
  for (int i = 0; i < 4; ++i)
#pragma unroll
    for (int j = 0; j < 4; ++j)
      acc[h * 4 + i][j] =
          __builtin_amdgcn_mfma_f32_16x16x32_bf16(af[i], bf[j], acc[h * 4 + i][j], 0, 0, 0);
  __builtin_amdgcn_s_setprio(0);
}

DEV void gemm_mainloop256(const u16* __restrict__ Ag, const u16* __restrict__ Bg,
                          int m0, int n0, u16* LdsA, u16* LdsB, f32x4 acc[8][4]) {
  const int tid = threadIdx.x, lane = tid & 63, wid = tid >> 6;
  const int wr = wid >> 2, wc = wid & 3;
  const int g0 = lane >> 4, l15 = lane & 15;

  auto AH = [&](int buf, int kk) { return LdsA + (buf * 2 + kk) * 8192; };
  auto BH = [&](int buf, int kk) { return LdsB + (buf * 2 + kk) * 8192; };

  // prologue: tile0 {Ak0,Bk0,Ak1,Bk1}, tile1 {Ak0,Bk0}  (6 halves, 12 loads)
  stage_half(Ag, m0, 0,  AH(0, 0), tid);
  stage_half(Bg, n0, 0,  BH(0, 0), tid);
  stage_half(Ag, m0, 32, AH(0, 1), tid);
  stage_half(Bg, n0, 32, BH(0, 1), tid);
  stage_half(Ag, m0, 64, AH(1, 0), tid);
  stage_half(Bg, n0, 64, BH(1, 0), tid);
  VM8;   // tile0 kk0 (A+B) landed; 4 newer halves stay in flight
  BAR();

  const int arow = wr * 128 + l15;
  const int brow = wc * 64 + l15;
  // row offsets (i*16, j*16, +64) are all 0 mod 8 -> one swizzle value per lane
  const int soff = (g0 ^ ((l15 >> 1) & 3)) * 8;
  bf16x8 af[4], bf[4];

#define LOADA(P, RB)                                                        \
  _Pragma("unroll") for (int i = 0; i < 4; ++i)                             \
      af[i] = *reinterpret_cast<const bf16x8*>((P) + (RB + i * 16) * 32 + soff)
#define LOADB(P)                                                            \
  _Pragma("unroll") for (int j = 0; j < 4; ++j)                             \
      bf[j] = *reinterpret_cast<const bf16x8*>((P) + (brow + j * 16) * 32 + soff)

  for (int v = 0; v < NKT; ++v) {
    const int par = v & 1;
    const u16* Ak0 = AH(par, 0); const u16* Ak1 = AH(par, 1);
    const u16* Bk0 = BH(par, 0); const u16* Bk1 = BH(par, 1);

    // ---- p0: af(h0,kk0)+bfr(kk0); stage A kk1 of tile v+1 -> other buf
    LOADA(Ak0, arow); LOADB(Bk0);
    if (v + 1 < NKT) stage_half(Ag, m0, (v + 1) * 64 + 32, AH(par ^ 1, 1), tid);
    LGKM0; __builtin_amdgcn_sched_barrier(0);
    mfma16(acc, af, bf, 0);
    BAR();

    // ---- p1: af(h1,kk0) (bfr kk0 kept in regs); stage B kk1 of v+1
    LOADA(Ak0, arow + 64);
    if (v + 1 < NKT) stage_half(Bg, n0, (v + 1) * 64 + 32, BH(par ^ 1, 1), tid);
    LGKM0; __builtin_amdgcn_sched_barrier(0);
    mfma16(acc, af, bf, 1);
    if (v < NKT - 1) { VM8; } else { VM0; }   // confirm kk1(v) landed
    BAR();

    // ---- p2: af(h0,kk1)+bfr(kk1); stage A kk0 of tile v+2 -> same buf (region free)
    LOADA(Ak1, arow); LOADB(Bk1);
    if (v + 2 < NKT) stage_half(Ag, m0, (v + 2) * 64, AH(par, 0), tid);
    LGKM0; __builtin_amdgcn_sched_barrier(0);
    mfma16(acc, af, bf, 0);
    BAR();

    // ---- p3: af(h1,kk1); stage B kk0 of v+2
    LOADA(Ak1, arow + 64);
    if (v + 2 < NKT) stage_half(Bg, n0, (v + 2) * 64, BH(par, 0), tid);
    LGKM0; __builtin_amdgcn_sched_barrier(0);
    mfma16(acc, af, bf, 1);
    if (v < NKT - 2) { VM8; BAR(); }          // confirm kk0(v+1) landed
    else if (v == NKT - 2) { VM4; BAR(); }
    // v == NKT-1: loop ends, nothing outstanding (VM0 at p1 drained)
  }
#undef LOADA
#undef LOADB
}

DEV int xcd_swizzle(int bid, int nwg) {   // nwg % 8 == 0 always here
  int cpx = nwg >> 3;
  return (bid & 7) * cpx + (bid >> 3);
}

// ---------------- projection GEMM: N = 3072 (dt | zpre | ya) ----------------
__global__ __launch_bounds__(512, 2) void gemm_proj_kernel(
    const u16* __restrict__ xb, const u16* __restrict__ Wcat,
    const float* __restrict__ b_dt, const float* __restrict__ b_lnz,
    const float* __restrict__ b_ya,
    u16* __restrict__ dtb, u16* __restrict__ zpb, u16* __restrict__ syab) {
  __shared__ __align__(16) u16 LdsA[2 * 2 * 8192];
  __shared__ __align__(16) u16 LdsB[2 * 2 * 8192];
  f32x4 acc[8][4] = {};

  constexpr int NT = 3 * D_ / 256;   // 12 n-tiles
  int swz = xcd_swizzle(blockIdx.x, gridDim.x);
  const int m0 = (swz / NT) * 256;
  const int n0 = (swz % NT) * 256;
  gemm_mainloop256(xb, Wcat, m0, n0, LdsA, LdsB, acc);

  const int tid = threadIdx.x, lane = tid & 63, wid = tid >> 6;
  const int wr = wid >> 2, wc = wid & 3;
  const int proj  = n0 >> 10;        // 256-tile lies fully inside one projection
  const int dbase = n0 & 1023;
  const float* bias = proj == 0 ? b_dt : (proj == 1 ? b_lnz : b_ya);
  u16* outp = proj == 0 ? dtb : (proj == 1 ? zpb : syab);
#pragma unroll
  for (int i = 0; i < 8; ++i) {
    int mr = m0 + wr * 128 + i * 16 + (lane >> 4) * 4;
#pragma unroll
    for (int j = 0; j < 4; ++j) {
      int nc = dbase + wc * 64 + j * 16 + (lane & 15);
      float bv = bias[nc];
#pragma unroll
      for (int r = 0; r < 4; ++r) {
        float v = acc[i][j][r] + bv;
        if (proj == 2) v = v / (1.f + __expf(-v));   // silu
        outp[(size_t)(mr + r) * D_ + nc] = f2bf(v);
      }
    }
  }
}

// ---------------- output GEMM: y = (h@w_y^T + b_y) * silu(ya) ----------------
__global__ __launch_bounds__(512, 2) void gemm_out_kernel(
    const u16* __restrict__ hb, const u16* __restrict__ Wyb,
    const float* __restrict__ b_y, const u16* __restrict__ syab,
    float* __restrict__ y) {
  __shared__ __align__(16) u16 LdsA[2 * 2 * 8192];
  __shared__ __align__(16) u16 LdsB[2 * 2 * 8192];
  f32x4 acc[8][4] = {};

  constexpr int NT = D_ / 256;       // 4 n-tiles
  int swz = xcd_swizzle(blockIdx.x, gridDim.x);
  const int m0 = (swz / NT) * 256;
  const int n0 = (swz % NT) * 256;
  gemm_mainloop256(hb, Wyb, m0, n0, LdsA, LdsB, acc);

  const int tid = threadIdx.x, lane = tid & 63, wid = tid >> 6;
  const int wr = wid >> 2, wc = wid & 3;
#pragma unroll
  for (int i = 0; i < 8; ++i) {
    int mr = m0 + wr * 128 + i * 16 + (lane >> 4) * 4;
#pragma unroll
    for (int j = 0; j < 4; ++j) {
      int nc = n0 + wc * 64 + j * 16 + (lane & 15);
      float bv = b_y[nc];
#pragma unroll
      for (int r = 0; r < 4; ++r) {
        float v = acc[i][j][r] + bv;
        float s = bf2f(syab[(size_t)(mr + r) * D_ + nc]);
        y[(size_t)(mr + r) * D_ + nc] = v * s;
      }
    }
  }
}

// ---------------- chunked scan: h_t = a_t h_{t-1} + z_t da_t ----------------
__global__ void scan1_kernel(const u16* __restrict__ dtb, const u16* __restrict__ zpb,
                             float* __restrict__ Ach, float* __restrict__ Bch) {
  const int b = blockIdx.x / CCH;
  const int c = blockIdx.x % CCH;
  const int d0 = threadIdx.x * 4;
  const size_t base = ((size_t)(b * L_ + c * TCH)) * D_ + d0;
  float h[4]  = {0.f, 0.f, 0.f, 0.f};
  float Ap[4] = {1.f, 1.f, 1.f, 1.f};
#pragma unroll 4
  for (int t = 0; t < TCH; ++t) {
    ushort4 du = *reinterpret_cast<const ushort4*>(dtb + base + (size_t)t * D_);
    ushort4 zu = *reinterpret_cast<const ushort4*>(zpb + base + (size_t)t * D_);
    const u16* dp = reinterpret_cast<const u16*>(&du);
    const u16* zz = reinterpret_cast<const u16*>(&zu);
#pragma unroll
    for (int q = 0; q < 4; ++q) {
      float dt = bf2f(dp[q]);
      float zv = bf2f(zz[q]);
      float a  = 1.f / (1.f + __expf(dt));    // sigmoid(-dt)
      float da = 1.f - a;                     // sigmoid(dt)
      float z  = 1.f / (1.f + __expf(-zv));   // sigmoid(zpre)
      h[q]  = a * h[q] + z * da;
      Ap[q] *= a;
    }
  }
  const size_t o = ((size_t)(b * CCH + c)) * D_ + d0;
  *reinterpret_cast<float4*>(Ach + o) = make_float4(Ap[0], Ap[1], Ap[2], Ap[3]);
  *reinterpret_cast<float4*>(Bch + o) = make_float4(h[0], h[1], h[2], h[3]);
}

__global__ void scan2_kernel(const float* __restrict__ Ach, const float* __restrict__ Bch,
                             const float* __restrict__ h0, float* __restrict__ Hin) {
  const int b = blockIdx.x >> 2;
  const int d = (blockIdx.x & 3) * 256 + threadIdx.x;
  float carry = h0[d];
  for (int c = 0; c < CCH; ++c) {
    const size_t o = ((size_t)(b * CCH + c)) * D_ + d;
    Hin[o] = carry;
    carry = Ach[o] * carry + Bch[o];
  }
}

__global__ void scan3_kernel(const u16* __restrict__ dtb, const u16* __restrict__ zpb,
                             const float* __restrict__ Hin, u16* __restrict__ hb) {
  const int b = blockIdx.x / CCH;
  const int c = blockIdx.x % CCH;
  const int d0 = threadIdx.x * 4;
  const size_t base = ((size_t)(b * L_ + c * TCH)) * D_ + d0;
  float4 hv = *reinterpret_cast<const float4*>(Hin + ((size_t)(b * CCH + c)) * D_ + d0);
  float h[4] = {hv.x, hv.y, hv.z, hv.w};
#pragma unroll 4
  for (int t = 0; t < TCH; ++t) {
    ushort4 du = *reinterpret_cast<const ushort4*>(dtb + base + (size_t)t * D_);
    ushort4 zu = *reinterpret_cast<const ushort4*>(zpb + base + (size_t)t * D_);
    const u16* dp = reinterpret_cast<const u16*>(&du);
    const u16* zz = reinterpret_cast<const u16*>(&zu);
    ushort4 ov;
    u16* op = reinterpret_cast<u16*>(&ov);
#pragma unroll
    for (int q = 0; q < 4; ++q) {
      float dt = bf2f(dp[q]);
      float zv = bf2f(zz[q]);
      float a  = 1.f / (1.f + __expf(dt));
      float da = 1.f - a;
      float z  = 1.f / (1.f + __expf(-zv));
      h[q] = a * h[q] + z * da;
      op[q] = f2bf(h[q]);
    }
    *reinterpret_cast<ushort4*>(hb + base + (size_t)t * D_) = ov;
  }
}

extern "C" void kernel_launch(void* const* d_in, const int* in_sizes, int n_in,
                              void* d_out, int out_size, void* d_ws, size_t ws_size,
                              hipStream_t stream) {
  const float* x     = (const float*)d_in[0];
  const float* w_lnz = (const float*)d_in[1];
  const float* b_lnz = (const float*)d_in[2];
  const float* w_dt  = (const float*)d_in[3];
  const float* b_dt  = (const float*)d_in[4];
  const float* w_y   = (const float*)d_in[5];
  const float* b_y   = (const float*)d_in[6];
  const float* w_ya  = (const float*)d_in[7];
  const float* b_ya  = (const float*)d_in[8];
  const float* h0    = (const float*)d_in[9];
  float* y = (float*)d_out;

  char* ws = (char*)d_ws;
  const size_t MB = 1024ull * 1024ull;
  u16*   xb   = (u16*)(ws);               // 64MB  bf16 x
  u16*   Wcat = (u16*)(ws + 64 * MB);     // 6MB   [w_dt; w_ln_z; w_ya]
  u16*   Wyb  = (u16*)(ws + 70 * MB);     // 2MB   w_y
  u16*   dtb  = (u16*)(ws + 72 * MB);     // 64MB
  u16*   zpb  = (u16*)(ws + 136 * MB);    // 64MB
  u16*   syab = (u16*)(ws + 200 * MB);    // 64MB  silu(ya)
  u16*   hb   = (u16*)(ws + 264 * MB);    // 64MB  h (bf16)
  float* Ach  = (float*)(ws + 328 * MB);  // 2MB
  float* Bch  = (float*)(ws + 330 * MB);  // 2MB
  float* Hin  = (float*)(ws + 332 * MB);  // 2MB

  // converts
  cvt_kernel<<<2048, 256, 0, stream>>>(x, xb, M_ * K_ / 8);
  cvt_w_kernel<<<1024, 256, 0, stream>>>(w_dt, w_lnz, w_ya, w_y, Wcat, Wyb);

  // fused 3-projection GEMM (256^2 tiles, 8-phase pipeline)
  gemm_proj_kernel<<<(M_ / 256) * (3 * D_ / 256), 512, 0, stream>>>(
      xb, Wcat, b_dt, b_lnz, b_ya, dtb, zpb, syab);

  // chunked scan
  scan1_kernel<<<B_ * CCH, 256, 0, stream>>>(dtb, zpb, Ach, Bch);
  scan2_kernel<<<16, 256, 0, stream>>>(Ach, Bch, h0, Hin);
  scan3_kernel<<<B_ * CCH, 256, 0, stream>>>(dtb, zpb, Hin, hb);

  // output GEMM fused with silu gate
  gemm_out_kernel<<<(M_ / 256) * (D_ / 256), 512, 0, stream>>>(
      hb, Wyb, b_y, syab, y);
}